// Round 2
// baseline (1619.180 us; speedup 1.0000x reference)
//
#include <hip/hip_runtime.h>
#include <hip/hip_bf16.h>
#include <math.h>

#define TT 2048
#define HID 2560
#define NH 40
#define NOPE 64
#define ROPE 32
#define VDIM 64
#define QLORA 768
#define KVLORA 256
#define DQK 288            // KVLORA + ROPE
#define QHD 96             // NOPE + ROPE
#define EPS 1e-5f
#define THETA 10000.0f

typedef __attribute__((ext_vector_type(8))) short bf16x8;
typedef __attribute__((ext_vector_type(4))) float f32x4;
typedef __attribute__((address_space(1))) const void* gas_t;
typedef __attribute__((address_space(3))) void* las_t;

static __device__ __forceinline__ ushort f2bf(float x) {
    __hip_bfloat16 b = __float2bfloat16(x);
    return *reinterpret_cast<ushort*>(&b);
}

// ---------------- flat fp32 -> bf16 cast ----------------
__global__ __launch_bounds__(256) void cast_bf16(const float* __restrict__ x,
                                                 ushort* __restrict__ y, int n) {
    int i = (blockIdx.x * 256 + threadIdx.x) * 4;
    if (i + 3 < n) {
        float4 v = *(const float4*)(x + i);
        y[i]     = f2bf(v.x);
        y[i + 1] = f2bf(v.y);
        y[i + 2] = f2bf(v.z);
        y[i + 3] = f2bf(v.w);
    }
}

// ------------- transpose + cast: w (K x N fp32) -> wt (N x K bf16) -------------
__global__ __launch_bounds__(256) void transpose_cast(const float* __restrict__ w,
                                                      ushort* __restrict__ wt,
                                                      int K, int N) {
    __shared__ float tile[32][33];
    int bn = blockIdx.x * 32, bk = blockIdx.y * 32;
    int tx = threadIdx.x % 32, ty = threadIdx.x / 32;   // 32 x 8
    #pragma unroll
    for (int i = 0; i < 32; i += 8) {
        int k = bk + ty + i, n = bn + tx;
        if (k < K && n < N) tile[ty + i][tx] = w[(size_t)k * N + n];
    }
    __syncthreads();
    #pragma unroll
    for (int i = 0; i < 32; i += 8) {
        int n = bn + ty + i, k = bk + tx;
        if (n < N && k < K) wt[(size_t)n * K + k] = f2bf(tile[tx][ty + i]);
    }
}

// ---- transpose V (bf16 -> bf16): kin_bf[T x 288] first 256 cols -> vtg[256 x T] ----
__global__ __launch_bounds__(256) void transpose_v(const ushort* __restrict__ kin_bf,
                                                   ushort* __restrict__ vtg) {
    __shared__ ushort tile[32][33];
    int bs = blockIdx.x * 32;   // s block
    int bv = blockIdx.y * 32;   // v block
    int tx = threadIdx.x % 32, ty = threadIdx.x / 32;  // 32 x 8
    #pragma unroll
    for (int i = 0; i < 32; i += 8)
        tile[ty + i][tx] = kin_bf[(size_t)(bs + ty + i) * DQK + bv + tx];
    __syncthreads();
    #pragma unroll
    for (int i = 0; i < 32; i += 8)
        vtg[(size_t)(bv + ty + i) * TT + bs + tx] = tile[tx][ty + i];
}

// ------- bf16 MFMA GEMM (m97 structure): C(MxN,f32) = A(MxK,bf16) @ Bt(NxK,bf16)^T -------
__global__ __launch_bounds__(256, 2) void gemm_bf16(const ushort* __restrict__ A,
                                                    const ushort* __restrict__ Bt,
                                                    float* __restrict__ C,
                                                    int M, int N, int K) {
    __shared__ ushort As[128 * 32];
    __shared__ ushort Bs[128 * 32];
    const int tid  = threadIdx.x;
    const int lane = tid & 63;
    const int wv   = tid >> 6;
    const int col  = lane & 15;
    const int quad = lane >> 4;
    const int m0 = blockIdx.y * 128, n0 = blockIdx.x * 128;
    const int wr = (wv >> 1) * 64, wc = (wv & 1) * 64;

    f32x4 acc[4][4];
    #pragma unroll
    for (int i = 0; i < 4; i++)
        #pragma unroll
        for (int j = 0; j < 4; j++) acc[i][j] = (f32x4){0.f, 0.f, 0.f, 0.f};

    for (int k0 = 0; k0 < K; k0 += 32) {
        #pragma unroll
        for (int j = 0; j < 2; j++) {
            int slot = wv * 128 + j * 64 + lane;     // 0..511
            int row  = slot >> 2;
            int ch   = slot & 3;
            const ushort* ga = A + (size_t)(m0 + row) * K + k0 + ch * 8;
            __builtin_amdgcn_global_load_lds((gas_t)ga, (las_t)(As + slot * 8), 16, 0, 0);
            int brow = n0 + row; if (brow >= N) brow = N - 1;   // clamp (edge tiles)
            const ushort* gb = Bt + (size_t)brow * K + k0 + ch * 8;
            __builtin_amdgcn_global_load_lds((gas_t)gb, (las_t)(Bs + slot * 8), 16, 0, 0);
        }
        __syncthreads();
        bf16x8 af[4], bfr[4];
        #pragma unroll
        for (int i = 0; i < 4; i++)
            af[i] = *(const bf16x8*)(As + (wr + i * 16 + col) * 32 + quad * 8);
        #pragma unroll
        for (int j = 0; j < 4; j++)
            bfr[j] = *(const bf16x8*)(Bs + (wc + j * 16 + col) * 32 + quad * 8);
        #pragma unroll
        for (int i = 0; i < 4; i++)
            #pragma unroll
            for (int j = 0; j < 4; j++)
                acc[i][j] = __builtin_amdgcn_mfma_f32_16x16x32_bf16(af[i], bfr[j], acc[i][j], 0, 0, 0);
        __syncthreads();
    }
    #pragma unroll
    for (int i = 0; i < 4; i++) {
        int gr = m0 + wr + i * 16 + quad * 4;
        #pragma unroll
        for (int j = 0; j < 4; j++) {
            int gc = n0 + wc + j * 16 + col;
            if (gc < N) {
                #pragma unroll
                for (int r = 0; r < 4; r++)
                    C[(size_t)(gr + r) * N + gc] = acc[i][j][r];
            }
        }
    }
}

// ---------------- RMS norm: fp32 in, bf16 out ----------------
__global__ __launch_bounds__(256) void rms_qa(const float* __restrict__ x,
                                              const float* __restrict__ g,
                                              ushort* __restrict__ y) {
    int t = blockIdx.x, tid = threadIdx.x;
    __shared__ float red[256];
    __shared__ float s_inv;
    const float* row = x + (size_t)t * QLORA;
    float ss = 0.f;
    for (int i = tid; i < QLORA; i += 256) { float v = row[i]; ss += v * v; }
    red[tid] = ss; __syncthreads();
    for (int s = 128; s > 0; s >>= 1) { if (tid < s) red[tid] += red[tid + s]; __syncthreads(); }
    if (tid == 0) s_inv = rsqrtf(red[0] / (float)QLORA + EPS);
    __syncthreads();
    float si = s_inv;
    ushort* orow = y + (size_t)t * QLORA;
    for (int i = tid; i < QLORA; i += 256) orow[i] = f2bf(row[i] * si * g[i]);
}

// ------- latent post: RMS first 256, RoPE last 32 -> bf16 kin_bf (T x 288) -------
__global__ __launch_bounds__(256) void kin_post(const float* __restrict__ kin,
                                                const float* __restrict__ g,
                                                const int* __restrict__ positions,
                                                ushort* __restrict__ kin_bf) {
    int t = blockIdx.x, tid = threadIdx.x;
    __shared__ float red[256];
    __shared__ float s_inv;
    const float* row = kin + (size_t)t * DQK;
    float v = row[tid];
    red[tid] = v * v; __syncthreads();
    for (int s = 128; s > 0; s >>= 1) { if (tid < s) red[tid] += red[tid + s]; __syncthreads(); }
    if (tid == 0) s_inv = rsqrtf(red[0] / (float)KVLORA + EPS);
    __syncthreads();
    ushort* orow = kin_bf + (size_t)t * DQK;
    orow[tid] = f2bf(v * s_inv * g[tid]);
    if (tid < 16) {
        float pos = (float)positions[t];
        float freq = powf(THETA, -(float)tid / 16.0f);
        float f = pos * freq;
        float c = cosf(f), s = sinf(f);
        float x1 = row[KVLORA + tid], x2 = row[KVLORA + 16 + tid];
        orow[KVLORA + tid]      = f2bf(x1 * c - x2 * s);
        orow[KVLORA + 16 + tid] = f2bf(x2 * c + x1 * s);
    }
}

// --- q_in build (tiled: 16 t-rows per block, w_kc[h] read once per block) ---
#define QTB 16
__global__ __launch_bounds__(256) void build_qin(const float* __restrict__ q,
                                                 const float* __restrict__ w_kc,
                                                 const int* __restrict__ positions,
                                                 ushort* __restrict__ qin) {
    int tb = blockIdx.x * QTB, h = blockIdx.y, tid = threadIdx.x;
    const float scale = 0.10206207261596577f;   // 1/sqrt(96), folded into Q
    __shared__ float qn[QTB][NOPE];
    __shared__ float qp[QTB][ROPE];
    // load 16 q rows (96 floats each)
    for (int i = tid; i < QTB * QHD; i += 256) {
        int r = i / QHD, cidx = i % QHD;
        float v = q[(size_t)(tb + r) * (NH * QHD) + h * QHD + cidx];
        if (cidx < NOPE) qn[r][cidx] = v;
        else             qp[r][cidx - NOPE] = v;
    }
    __syncthreads();
    // each thread owns one latent dim k for all 16 rows
    int k = tid;
    float acc[QTB];
    #pragma unroll
    for (int r = 0; r < QTB; r++) acc[r] = 0.f;
    const float* w = w_kc + (size_t)h * NOPE * KVLORA + k;
    for (int n = 0; n < NOPE; n++) {
        float wval = w[(size_t)n * KVLORA];
        #pragma unroll
        for (int r = 0; r < QTB; r++) acc[r] += qn[r][n] * wval;
    }
    #pragma unroll
    for (int r = 0; r < QTB; r++)
        qin[((size_t)(tb + r) * NH + h) * DQK + k] = f2bf(acc[r] * scale);
    // rope: 16 rows x 16 freqs = 256 threads
    int r = tid >> 4, fi = tid & 15;
    float pos = (float)positions[tb + r];
    float freq = powf(THETA, -(float)fi / 16.0f);
    float f = pos * freq;
    float c = cosf(f), s = sinf(f);
    float x1 = qp[r][fi], x2 = qp[r][16 + fi];
    ushort* orow = qin + ((size_t)(tb + r) * NH + h) * DQK;
    orow[KVLORA + fi]      = f2bf((x1 * c - x2 * s) * scale);
    orow[KVLORA + 16 + fi] = f2bf((x2 * c + x1 * s) * scale);
}

// ---------------- flash MFMA attention (barrier-free, direct-L2 fragments) ----------------
// K and V working sets (kin_bf 1.18 MB, vtg 1 MB) are L2-resident: read MFMA B-fragments
// directly from global (16 rows x 64B contiguous per load, 4-lane coalesced). No K/V LDS,
// no __syncthreads anywhere; only per-wave-private P buffer in LDS. 3 blocks/CU.
#define PSTR 72

__global__ __launch_bounds__(256, 3) void flash_attn(const ushort* __restrict__ qin,
                                                     const ushort* __restrict__ kin,
                                                     const ushort* __restrict__ vtg,
                                                     float* __restrict__ o_lat) {
    __shared__ __align__(16) ushort pbuf[64 * PSTR];   // per-wave private rows

    const int tid  = threadIdx.x;
    const int lane = tid & 63;
    const int wv   = tid >> 6;
    const int col  = lane & 15;
    const int quad = lane >> 4;
    const int h    = blockIdx.y;
    const int qb   = ((int)gridDim.x - 1 - (int)blockIdx.x) * 64;

    bf16x8 qf[9];
    {
        const ushort* base = qin + ((size_t)(qb + wv * 16 + col) * NH + h) * DQK + quad * 8;
        #pragma unroll
        for (int k = 0; k < 9; k++) qf[k] = *(const bf16x8*)(base + k * 32);
    }

    f32x4 of[16];
    #pragma unroll
    for (int i = 0; i < 16; i++) of[i] = (f32x4){0.f, 0.f, 0.f, 0.f};
    float m_i[4] = {-1e30f, -1e30f, -1e30f, -1e30f};
    float l_i[4] = {0.f, 0.f, 0.f, 0.f};

    for (int s0 = 0; s0 <= qb; s0 += 64) {
        // ---- QK^T: B-fragments straight from kin (L2) ----
        const ushort* kr0 = kin + (size_t)(s0 +  0 + col) * DQK + quad * 8;
        const ushort* kr1 = kin + (size_t)(s0 + 16 + col) * DQK + quad * 8;
        const ushort* kr2 = kin + (size_t)(s0 + 32 + col) * DQK + quad * 8;
        const ushort* kr3 = kin + (size_t)(s0 + 48 + col) * DQK + quad * 8;
        f32x4 sf[4];
        #pragma unroll
        for (int tc = 0; tc < 4; tc++) sf[tc] = (f32x4){0.f, 0.f, 0.f, 0.f};
        __builtin_amdgcn_s_setprio(1);
        #pragma unroll
        for (int k = 0; k < 9; k++) {
            bf16x8 b0 = *(const bf16x8*)(kr0 + k * 32);
            bf16x8 b1 = *(const bf16x8*)(kr1 + k * 32);
            bf16x8 b2 = *(const bf16x8*)(kr2 + k * 32);
            bf16x8 b3 = *(const bf16x8*)(kr3 + k * 32);
            sf[0] = __builtin_amdgcn_mfma_f32_16x16x32_bf16(qf[k], b0, sf[0], 0, 0, 0);
            sf[1] = __builtin_amdgcn_mfma_f32_16x16x32_bf16(qf[k], b1, sf[1], 0, 0, 0);
            sf[2] = __builtin_amdgcn_mfma_f32_16x16x32_bf16(qf[k], b2, sf[2], 0, 0, 0);
            sf[3] = __builtin_amdgcn_mfma_f32_16x16x32_bf16(qf[k], b3, sf[3], 0, 0, 0);
        }
        __builtin_amdgcn_s_setprio(0);

        if (s0 == qb) {
            #pragma unroll
            for (int tc = 0; tc < 4; tc++)
                #pragma unroll
                for (int r = 0; r < 4; r++)
                    if (tc * 16 + col > wv * 16 + quad * 4 + r) sf[tc][r] = -1e30f;
        }
        float mnew[4], alpha[4];
        #pragma unroll
        for (int r = 0; r < 4; r++) {
            float mx = fmaxf(fmaxf(sf[0][r], sf[1][r]), fmaxf(sf[2][r], sf[3][r]));
            mx = fmaxf(mx, __shfl_xor(mx, 1));
            mx = fmaxf(mx, __shfl_xor(mx, 2));
            mx = fmaxf(mx, __shfl_xor(mx, 4));
            mx = fmaxf(mx, __shfl_xor(mx, 8));
            mnew[r] = fmaxf(m_i[r], mx);
            alpha[r] = __expf(m_i[r] - mnew[r]);
            m_i[r] = mnew[r];
        }
        float rsum[4];
        #pragma unroll
        for (int r = 0; r < 4; r++) {
            float s = 0.f;
            #pragma unroll
            for (int tc = 0; tc < 4; tc++) {
                float p = __expf(sf[tc][r] - mnew[r]);
                sf[tc][r] = p;
                s += p;
            }
            s += __shfl_xor(s, 1);
            s += __shfl_xor(s, 2);
            s += __shfl_xor(s, 4);
            s += __shfl_xor(s, 8);
            rsum[r] = s;
        }
        #pragma unroll
        for (int r = 0; r < 4; r++) l_i[r] = l_i[r] * alpha[r] + rsum[r];
        #pragma unroll
        for (int i = 0; i < 16; i++)
            #pragma unroll
            for (int r = 0; r < 4; r++) of[i][r] *= alpha[r];

        // ---- P -> pbuf (per-wave private rows: no barrier needed) ----
        #pragma unroll
        for (int tc = 0; tc < 4; tc++)
            #pragma unroll
            for (int r = 0; r < 4; r++)
                pbuf[(wv * 16 + quad * 4 + r) * PSTR + tc * 16 + col] = f2bf(sf[tc][r]);
        bf16x8 pa[2];
        #pragma unroll
        for (int ks = 0; ks < 2; ks++)
            pa[ks] = *(const bf16x8*)(pbuf + (wv * 16 + col) * PSTR + ks * 32 + quad * 8);

        // ---- PV: B-fragments straight from vtg (L2) ----
        __builtin_amdgcn_s_setprio(1);
        #pragma unroll
        for (int nt = 0; nt < 16; nt++) {
            const ushort* vr = vtg + (size_t)(nt * 16 + col) * TT + s0 + quad * 8;
            bf16x8 v0 = *(const bf16x8*)(vr);
            bf16x8 v1 = *(const bf16x8*)(vr + 32);
            of[nt] = __builtin_amdgcn_mfma_f32_16x16x32_bf16(pa[0], v0, of[nt], 0, 0, 0);
            of[nt] = __builtin_amdgcn_mfma_f32_16x16x32_bf16(pa[1], v1, of[nt], 0, 0, 0);
        }
        __builtin_amdgcn_s_setprio(0);
    }
    #pragma unroll
    for (int r = 0; r < 4; r++) {
        float inv = 1.0f / l_i[r];
        int row = qb + wv * 16 + quad * 4 + r;
        float* dst = o_lat + ((size_t)row * NH + h) * KVLORA + col;
        #pragma unroll
        for (int nt = 0; nt < 16; nt++) dst[nt * 16] = of[nt][r] * inv;
    }
}

// ------- o_bf = o_lat @ w_vc[h] (tiled: 16 t-rows per block, w_vc[h] read once) -------
__global__ __launch_bounds__(256) void ogemm(const float* __restrict__ o_lat,
                                             const float* __restrict__ w_vc,
                                             ushort* __restrict__ o) {
    int tb = blockIdx.x * 16, h = blockIdx.y, tid = threadIdx.x;
    __shared__ float ol[16][KVLORA];
    for (int i = tid; i < 16 * KVLORA; i += 256) {
        int r = i >> 8, k = i & 255;
        ol[r][k] = o_lat[((size_t)(tb + r) * NH + h) * KVLORA + k];
    }
    __syncthreads();
    int v = tid & 63, r0 = tid >> 6;       // 4 rows/thread: r0, r0+4, r0+8, r0+12
    float acc[4] = {0.f, 0.f, 0.f, 0.f};
    const float* w = w_vc + (size_t)h * KVLORA * VDIM + v;
    for (int k = 0; k < KVLORA; k++) {
        float wval = w[(size_t)k * VDIM];
        #pragma unroll
        for (int j = 0; j < 4; j++) acc[j] += ol[r0 + j * 4][k] * wval;
    }
    #pragma unroll
    for (int j = 0; j < 4; j++)
        o[(size_t)(tb + r0 + j * 4) * HID + h * VDIM + v] = f2bf(acc[j]);
}

extern "C" void kernel_launch(void* const* d_in, const int* in_sizes, int n_in,
                              void* d_out, int out_size, void* d_ws, size_t ws_size,
                              hipStream_t stream) {
    const int*   positions = (const int*)d_in[0];
    const float* hs    = (const float*)d_in[1];
    const float* w_qa  = (const float*)d_in[2];
    const float* g_qa  = (const float*)d_in[3];
    const float* w_qb  = (const float*)d_in[4];
    const float* w_kva = (const float*)d_in[5];
    const float* g_kva = (const float*)d_in[6];
    const float* w_kc  = (const float*)d_in[7];
    const float* w_vc  = (const float*)d_in[8];
    const float* w_o   = (const float*)d_in[9];
    float* out = (float*)d_out;

    float* ws    = (float*)d_ws;
    float* qa    = ws;                               // T*768
    float* q     = qa    + (size_t)TT * QLORA;       // T*3840
    float* kin   = q     + (size_t)TT * NH * QHD;    // T*288
    float* o_lat = kin   + (size_t)TT * DQK;         // T*40*256
    ushort* ub     = (ushort*)(o_lat + (size_t)TT * NH * KVLORA);
    ushort* hs_bf  = ub;                             // T*2560
    ushort* qa_bf  = hs_bf  + (size_t)TT * HID;      // T*768
    ushort* o_bf   = qa_bf  + (size_t)TT * QLORA;    // T*2560
    ushort* kin_bf = o_bf   + (size_t)TT * HID;      // T*288
    ushort* qin_bf = kin_bf + (size_t)TT * DQK;      // T*40*288
    ushort* w_qa_t  = qin_bf + (size_t)TT * NH * DQK;       // 768*2560
    ushort* w_qb_t  = w_qa_t + (size_t)QLORA * HID;         // 3840*768
    ushort* w_kva_t = w_qb_t + (size_t)(NH * QHD) * QLORA;  // 288*2560
    ushort* w_o_t   = w_kva_t + (size_t)DQK * HID;          // 2560*2560
    ushort* vtg     = w_o_t + (size_t)HID * HID;            // 256*2048

    // ---- casts / transposes (independent of each other) ----
    cast_bf16<<<(TT * HID) / 1024, 256, 0, stream>>>(hs, hs_bf, TT * HID);
    transpose_cast<<<dim3(QLORA / 32, HID / 32), 256, 0, stream>>>(w_qa, w_qa_t, HID, QLORA);
    transpose_cast<<<dim3((NH * QHD) / 32, QLORA / 32), 256, 0, stream>>>(w_qb, w_qb_t, QLORA, NH * QHD);
    transpose_cast<<<dim3(DQK / 32, HID / 32), 256, 0, stream>>>(w_kva, w_kva_t, HID, DQK);
    transpose_cast<<<dim3(HID / 32, HID / 32), 256, 0, stream>>>(w_o, w_o_t, HID, HID);

    // 1. qa = hs @ w_qa (MFMA); RMS -> qa_bf
    gemm_bf16<<<dim3(QLORA / 128, TT / 128), 256, 0, stream>>>(hs_bf, w_qa_t, qa, TT, QLORA, HID);
    rms_qa<<<TT, 256, 0, stream>>>(qa, g_qa, qa_bf);
    // 2. q = qa @ w_qb (MFMA)
    gemm_bf16<<<dim3((NH * QHD) / 128, TT / 128), 256, 0, stream>>>(qa_bf, w_qb_t, q, TT, NH * QHD, QLORA);
    // 3. kin = hs @ w_kva (MFMA, N=288 edge); RMS+RoPE -> kin_bf
    gemm_bf16<<<dim3((DQK + 127) / 128, TT / 128), 256, 0, stream>>>(hs_bf, w_kva_t, kin, TT, DQK, HID);
    kin_post<<<TT, 256, 0, stream>>>(kin, g_kva, positions, kin_bf);
    // 3b. vtg = transpose of v_in (direct V^T fragment source for attention)
    transpose_v<<<dim3(TT / 32, KVLORA / 32), 256, 0, stream>>>(kin_bf, vtg);
    // 4. qin_bf = [q_nope @ w_kc[h] | rope(q_pe)] * scale
    build_qin<<<dim3(TT / QTB, NH), 256, 0, stream>>>(q, w_kc, positions, qin_bf);
    // 5. flash MFMA attention (barrier-free)
    flash_attn<<<dim3(TT / 64, NH), 256, 0, stream>>>(qin_bf, kin_bf, vtg, o_lat);
    // 6. o_bf = o_lat @ w_vc
    ogemm<<<dim3(TT / 16, NH), 256, 0, stream>>>(o_lat, w_vc, o_bf);
    // 7. out = o_bf @ w_o (MFMA)
    gemm_bf16<<<dim3(HID / 128, TT / 128), 256, 0, stream>>>(o_bf, w_o_t, out, TT, HID, HID);
}

// Round 3
// 1290.220 us; speedup vs baseline: 1.2550x; 1.2550x over previous
//
#include <hip/hip_runtime.h>
#include <hip/hip_bf16.h>
#include <math.h>

#define TT 2048
#define HID 2560
#define NH 40
#define NOPE 64
#define ROPE 32
#define VDIM 64
#define QLORA 768
#define KVLORA 256
#define DQK 288            // KVLORA + ROPE
#define QHD 96             // NOPE + ROPE
#define EPS 1e-5f
#define THETA 10000.0f

typedef __attribute__((ext_vector_type(8))) short bf16x8;
typedef __attribute__((ext_vector_type(4))) float f32x4;
typedef __attribute__((address_space(1))) const void* gas_t;
typedef __attribute__((address_space(3))) void* las_t;

static __device__ __forceinline__ ushort f2bf(float x) {
    __hip_bfloat16 b = __float2bfloat16(x);
    return *reinterpret_cast<ushort*>(&b);
}

// ---------------- flat fp32 -> bf16 cast ----------------
__global__ __launch_bounds__(256) void cast_bf16(const float* __restrict__ x,
                                                 ushort* __restrict__ y, int n) {
    int i = (blockIdx.x * 256 + threadIdx.x) * 4;
    if (i + 3 < n) {
        float4 v = *(const float4*)(x + i);
        y[i]     = f2bf(v.x);
        y[i + 1] = f2bf(v.y);
        y[i + 2] = f2bf(v.z);
        y[i + 3] = f2bf(v.w);
    }
}

// ------------- transpose + cast: w (K x N fp32) -> wt (N x K bf16) -------------
__global__ __launch_bounds__(256) void transpose_cast(const float* __restrict__ w,
                                                      ushort* __restrict__ wt,
                                                      int K, int N) {
    __shared__ float tile[32][33];
    int bn = blockIdx.x * 32, bk = blockIdx.y * 32;
    int tx = threadIdx.x % 32, ty = threadIdx.x / 32;   // 32 x 8
    #pragma unroll
    for (int i = 0; i < 32; i += 8) {
        int k = bk + ty + i, n = bn + tx;
        if (k < K && n < N) tile[ty + i][tx] = w[(size_t)k * N + n];
    }
    __syncthreads();
    #pragma unroll
    for (int i = 0; i < 32; i += 8) {
        int n = bn + ty + i, k = bk + tx;
        if (n < N && k < K) wt[(size_t)n * K + k] = f2bf(tile[tx][ty + i]);
    }
}

// ---- transpose V (bf16 -> bf16): kin_bf[T x 288] first 256 cols -> vtg[256 x T] ----
__global__ __launch_bounds__(256) void transpose_v(const ushort* __restrict__ kin_bf,
                                                   ushort* __restrict__ vtg) {
    __shared__ ushort tile[32][33];
    int bs = blockIdx.x * 32;   // s block
    int bv = blockIdx.y * 32;   // v block
    int tx = threadIdx.x % 32, ty = threadIdx.x / 32;  // 32 x 8
    #pragma unroll
    for (int i = 0; i < 32; i += 8)
        tile[ty + i][tx] = kin_bf[(size_t)(bs + ty + i) * DQK + bv + tx];
    __syncthreads();
    #pragma unroll
    for (int i = 0; i < 32; i += 8)
        vtg[(size_t)(bv + ty + i) * TT + bs + tx] = tile[tx][ty + i];
}

// ------- bf16 MFMA GEMM (m97 structure): C(MxN,f32) = A(MxK,bf16) @ Bt(NxK,bf16)^T -------
__global__ __launch_bounds__(256, 2) void gemm_bf16(const ushort* __restrict__ A,
                                                    const ushort* __restrict__ Bt,
                                                    float* __restrict__ C,
                                                    int M, int N, int K) {
    __shared__ ushort As[128 * 32];
    __shared__ ushort Bs[128 * 32];
    const int tid  = threadIdx.x;
    const int lane = tid & 63;
    const int wv   = tid >> 6;
    const int col  = lane & 15;
    const int quad = lane >> 4;
    const int m0 = blockIdx.y * 128, n0 = blockIdx.x * 128;
    const int wr = (wv >> 1) * 64, wc = (wv & 1) * 64;

    f32x4 acc[4][4];
    #pragma unroll
    for (int i = 0; i < 4; i++)
        #pragma unroll
        for (int j = 0; j < 4; j++) acc[i][j] = (f32x4){0.f, 0.f, 0.f, 0.f};

    for (int k0 = 0; k0 < K; k0 += 32) {
        #pragma unroll
        for (int j = 0; j < 2; j++) {
            int slot = wv * 128 + j * 64 + lane;     // 0..511
            int row  = slot >> 2;
            int ch   = slot & 3;
            const ushort* ga = A + (size_t)(m0 + row) * K + k0 + ch * 8;
            __builtin_amdgcn_global_load_lds((gas_t)ga, (las_t)(As + slot * 8), 16, 0, 0);
            int brow = n0 + row; if (brow >= N) brow = N - 1;   // clamp (edge tiles)
            const ushort* gb = Bt + (size_t)brow * K + k0 + ch * 8;
            __builtin_amdgcn_global_load_lds((gas_t)gb, (las_t)(Bs + slot * 8), 16, 0, 0);
        }
        __syncthreads();
        bf16x8 af[4], bfr[4];
        #pragma unroll
        for (int i = 0; i < 4; i++)
            af[i] = *(const bf16x8*)(As + (wr + i * 16 + col) * 32 + quad * 8);
        #pragma unroll
        for (int j = 0; j < 4; j++)
            bfr[j] = *(const bf16x8*)(Bs + (wc + j * 16 + col) * 32 + quad * 8);
        #pragma unroll
        for (int i = 0; i < 4; i++)
            #pragma unroll
            for (int j = 0; j < 4; j++)
                acc[i][j] = __builtin_amdgcn_mfma_f32_16x16x32_bf16(af[i], bfr[j], acc[i][j], 0, 0, 0);
        __syncthreads();
    }
    #pragma unroll
    for (int i = 0; i < 4; i++) {
        int gr = m0 + wr + i * 16 + quad * 4;
        #pragma unroll
        for (int j = 0; j < 4; j++) {
            int gc = n0 + wc + j * 16 + col;
            if (gc < N) {
                #pragma unroll
                for (int r = 0; r < 4; r++)
                    C[(size_t)(gr + r) * N + gc] = acc[i][j][r];
            }
        }
    }
}

// ---------------- RMS norm: fp32 in, bf16 out ----------------
__global__ __launch_bounds__(256) void rms_qa(const float* __restrict__ x,
                                              const float* __restrict__ g,
                                              ushort* __restrict__ y) {
    int t = blockIdx.x, tid = threadIdx.x;
    __shared__ float red[256];
    __shared__ float s_inv;
    const float* row = x + (size_t)t * QLORA;
    float ss = 0.f;
    for (int i = tid; i < QLORA; i += 256) { float v = row[i]; ss += v * v; }
    red[tid] = ss; __syncthreads();
    for (int s = 128; s > 0; s >>= 1) { if (tid < s) red[tid] += red[tid + s]; __syncthreads(); }
    if (tid == 0) s_inv = rsqrtf(red[0] / (float)QLORA + EPS);
    __syncthreads();
    float si = s_inv;
    ushort* orow = y + (size_t)t * QLORA;
    for (int i = tid; i < QLORA; i += 256) orow[i] = f2bf(row[i] * si * g[i]);
}

// ------- latent post: RMS first 256, RoPE last 32 -> bf16 kin_bf (T x 288) -------
__global__ __launch_bounds__(256) void kin_post(const float* __restrict__ kin,
                                                const float* __restrict__ g,
                                                const int* __restrict__ positions,
                                                ushort* __restrict__ kin_bf) {
    int t = blockIdx.x, tid = threadIdx.x;
    __shared__ float red[256];
    __shared__ float s_inv;
    const float* row = kin + (size_t)t * DQK;
    float v = row[tid];
    red[tid] = v * v; __syncthreads();
    for (int s = 128; s > 0; s >>= 1) { if (tid < s) red[tid] += red[tid + s]; __syncthreads(); }
    if (tid == 0) s_inv = rsqrtf(red[0] / (float)KVLORA + EPS);
    __syncthreads();
    ushort* orow = kin_bf + (size_t)t * DQK;
    orow[tid] = f2bf(v * s_inv * g[tid]);
    if (tid < 16) {
        float pos = (float)positions[t];
        float freq = powf(THETA, -(float)tid / 16.0f);
        float f = pos * freq;
        float c = cosf(f), s = sinf(f);
        float x1 = row[KVLORA + tid], x2 = row[KVLORA + 16 + tid];
        orow[KVLORA + tid]      = f2bf(x1 * c - x2 * s);
        orow[KVLORA + 16 + tid] = f2bf(x2 * c + x1 * s);
    }
}

// --- q_in build (tiled: 16 t-rows per block, w_kc[h] read once per block) ---
#define QTB 16
__global__ __launch_bounds__(256) void build_qin(const float* __restrict__ q,
                                                 const float* __restrict__ w_kc,
                                                 const int* __restrict__ positions,
                                                 ushort* __restrict__ qin) {
    int tb = blockIdx.x * QTB, h = blockIdx.y, tid = threadIdx.x;
    const float scale = 0.10206207261596577f;   // 1/sqrt(96), folded into Q
    __shared__ float qn[QTB][NOPE];
    __shared__ float qp[QTB][ROPE];
    // load 16 q rows (96 floats each)
    for (int i = tid; i < QTB * QHD; i += 256) {
        int r = i / QHD, cidx = i % QHD;
        float v = q[(size_t)(tb + r) * (NH * QHD) + h * QHD + cidx];
        if (cidx < NOPE) qn[r][cidx] = v;
        else             qp[r][cidx - NOPE] = v;
    }
    __syncthreads();
    // each thread owns one latent dim k for all 16 rows
    int k = tid;
    float acc[QTB];
    #pragma unroll
    for (int r = 0; r < QTB; r++) acc[r] = 0.f;
    const float* w = w_kc + (size_t)h * NOPE * KVLORA + k;
    for (int n = 0; n < NOPE; n++) {
        float wval = w[(size_t)n * KVLORA];
        #pragma unroll
        for (int r = 0; r < QTB; r++) acc[r] += qn[r][n] * wval;
    }
    #pragma unroll
    for (int r = 0; r < QTB; r++)
        qin[((size_t)(tb + r) * NH + h) * DQK + k] = f2bf(acc[r] * scale);
    // rope: 16 rows x 16 freqs = 256 threads
    int r = tid >> 4, fi = tid & 15;
    float pos = (float)positions[tb + r];
    float freq = powf(THETA, -(float)fi / 16.0f);
    float f = pos * freq;
    float c = cosf(f), s = sinf(f);
    float x1 = qp[r][fi], x2 = qp[r][16 + fi];
    ushort* orow = qin + ((size_t)(tb + r) * NH + h) * DQK;
    orow[KVLORA + fi]      = f2bf((x1 * c - x2 * s) * scale);
    orow[KVLORA + 16 + fi] = f2bf((x2 * c + x1 * s) * scale);
}

// ---------------- flash MFMA attention ----------------
// T14 async-split register staging: global loads for tile t+1 issue during compute of
// tile t (loop-carried register dep -> compiler cannot drain them early). LDS layouts
// XOR-swizzled on the ds_write side (reg staging frees us from gload_lds linear-dest):
//   K256: 64 rows x 512B, slot = ch ^ (row&7)      -> b128 read/write 8 lanes/16B-group (optimal)
//   Vt:  256 rows x 128B, slot = ch ^ (v&7)        -> same
//   rope: 64 rows x 96B (16B-aligned)
// pbuf dedicated per-wave rows (no barriers around P). 2 barriers/iter, no vmcnt(0) drain.
#define RSTR 48
#define PSTR 72

__global__ __launch_bounds__(256, 2) void flash_attn(const ushort* __restrict__ qin,
                                                     const ushort* __restrict__ kin,
                                                     const ushort* __restrict__ vtg,
                                                     float* __restrict__ o_lat) {
    __shared__ __align__(16) ushort lds[64 * 256 + 256 * 64 + 64 * RSTR + 64 * PSTR];
    ushort* k256  = lds;                          // 32768 B
    ushort* vtb   = lds + 64 * 256;               // 32768 B
    ushort* krope = vtb + 256 * 64;               // 6144 B
    ushort* pbuf  = krope + 64 * RSTR;            // 9216 B   (total 80896 B -> 2 blocks/CU)

    const int tid  = threadIdx.x;
    const int lane = tid & 63;
    const int wv   = tid >> 6;
    const int col  = lane & 15;
    const int quad = lane >> 4;
    const int h    = blockIdx.y;
    const int qb   = ((int)gridDim.x - 1 - (int)blockIdx.x) * 64;

    // staging geometry (constant per thread)
    const int krow_s = tid >> 2;          // 0..63   (K + rope row)
    const int kpart  = tid & 3;           // 0..3    (K: 4 threads/row, 128B each)
    const int rch    = tid & 3;           // rope chunk
    const int vrow_b = tid >> 3;          // 0..31   (V: vrow = j*32 + vrow_b)
    const int vch    = tid & 7;           // V chunk in row

    bf16x8 qf[9];
    {
        const ushort* base = qin + ((size_t)(qb + wv * 16 + col) * NH + h) * DQK + quad * 8;
        #pragma unroll
        for (int k = 0; k < 9; k++) qf[k] = *(const bf16x8*)(base + k * 32);
    }

    f32x4 of[16];
    #pragma unroll
    for (int i = 0; i < 16; i++) of[i] = (f32x4){0.f, 0.f, 0.f, 0.f};
    float m_i[4] = {-1e30f, -1e30f, -1e30f, -1e30f};
    float l_i[4] = {0.f, 0.f, 0.f, 0.f};

    uint4 kreg[8], vreg[8], rreg;

#define STAGE_LOAD(S0) do {                                                         \
        const ushort* kb_ = kin + ((size_t)(S0) + krow_s) * DQK;                    \
        _Pragma("unroll")                                                           \
        for (int j_ = 0; j_ < 8; j_++)                                              \
            kreg[j_] = *(const uint4*)(kb_ + kpart * 64 + j_ * 8);                  \
        rreg = *(const uint4*)(kb_ + KVLORA + rch * 8);                             \
        const ushort* vb_ = vtg + (size_t)vrow_b * TT + (S0) + vch * 8;             \
        _Pragma("unroll")                                                           \
        for (int j_ = 0; j_ < 8; j_++)                                              \
            vreg[j_] = *(const uint4*)(vb_ + (size_t)j_ * 32 * TT);                 \
    } while (0)

#define STAGE_WRITE() do {                                                          \
        _Pragma("unroll")                                                           \
        for (int j_ = 0; j_ < 8; j_++)                                              \
            *(uint4*)((char*)k256 + krow_s * 512 +                                  \
                      ((((kpart << 3) + j_) ^ (krow_s & 7)) << 4)) = kreg[j_];      \
        *(uint4*)((char*)krope + krow_s * 96 + rch * 16) = rreg;                    \
        _Pragma("unroll")                                                           \
        for (int j_ = 0; j_ < 8; j_++)                                              \
            *(uint4*)((char*)vtb + (j_ * 32 + vrow_b) * 128 +                       \
                      ((vch ^ (vrow_b & 7)) << 4)) = vreg[j_];                      \
    } while (0)

    STAGE_LOAD(0);

    for (int s0 = 0; s0 <= qb; s0 += 64) {
        __syncthreads();                     // all waves done reading prev tile
        STAGE_WRITE();                       // compiler waits vmcnt for the regs
        if (s0 + 64 <= qb) STAGE_LOAD(s0 + 64);   // prefetch next tile (in flight across compute)
        __syncthreads();                     // tile visible

        // ---- QK^T ----
        f32x4 sf[4];
        #pragma unroll
        for (int tc = 0; tc < 4; tc++) sf[tc] = (f32x4){0.f, 0.f, 0.f, 0.f};
        __builtin_amdgcn_s_setprio(1);
        #pragma unroll
        for (int k = 0; k < 8; k++) {
            #pragma unroll
            for (int tc = 0; tc < 4; tc++) {
                int row = tc * 16 + col;
                bf16x8 bf = *(const bf16x8*)((const char*)k256 + row * 512 +
                                             ((((k << 2) + quad) ^ (col & 7)) << 4));
                sf[tc] = __builtin_amdgcn_mfma_f32_16x16x32_bf16(qf[k], bf, sf[tc], 0, 0, 0);
            }
        }
        #pragma unroll
        for (int tc = 0; tc < 4; tc++) {
            bf16x8 bf = *(const bf16x8*)(krope + (tc * 16 + col) * RSTR + quad * 8);
            sf[tc] = __builtin_amdgcn_mfma_f32_16x16x32_bf16(qf[8], bf, sf[tc], 0, 0, 0);
        }
        __builtin_amdgcn_s_setprio(0);

        if (s0 == qb) {
            #pragma unroll
            for (int tc = 0; tc < 4; tc++)
                #pragma unroll
                for (int r = 0; r < 4; r++)
                    if (tc * 16 + col > wv * 16 + quad * 4 + r) sf[tc][r] = -1e30f;
        }
        float mnew[4], alpha[4];
        #pragma unroll
        for (int r = 0; r < 4; r++) {
            float mx = fmaxf(fmaxf(sf[0][r], sf[1][r]), fmaxf(sf[2][r], sf[3][r]));
            mx = fmaxf(mx, __shfl_xor(mx, 1));
            mx = fmaxf(mx, __shfl_xor(mx, 2));
            mx = fmaxf(mx, __shfl_xor(mx, 4));
            mx = fmaxf(mx, __shfl_xor(mx, 8));
            mnew[r] = fmaxf(m_i[r], mx);
            alpha[r] = __expf(m_i[r] - mnew[r]);
            m_i[r] = mnew[r];
        }
        float rsum[4];
        #pragma unroll
        for (int r = 0; r < 4; r++) {
            float s = 0.f;
            #pragma unroll
            for (int tc = 0; tc < 4; tc++) {
                float p = __expf(sf[tc][r] - mnew[r]);
                sf[tc][r] = p;
                s += p;
            }
            s += __shfl_xor(s, 1);
            s += __shfl_xor(s, 2);
            s += __shfl_xor(s, 4);
            s += __shfl_xor(s, 8);
            rsum[r] = s;
        }
        #pragma unroll
        for (int r = 0; r < 4; r++) l_i[r] = l_i[r] * alpha[r] + rsum[r];
        #pragma unroll
        for (int i = 0; i < 16; i++)
            #pragma unroll
            for (int r = 0; r < 4; r++) of[i][r] *= alpha[r];

        // ---- P -> pbuf (per-wave private rows: no barrier needed) ----
        #pragma unroll
        for (int tc = 0; tc < 4; tc++)
            #pragma unroll
            for (int r = 0; r < 4; r++)
                pbuf[(wv * 16 + quad * 4 + r) * PSTR + tc * 16 + col] = f2bf(sf[tc][r]);
        bf16x8 pa[2];
        #pragma unroll
        for (int ks = 0; ks < 2; ks++)
            pa[ks] = *(const bf16x8*)(pbuf + (wv * 16 + col) * PSTR + ks * 32 + quad * 8);

        // ---- PV ----
        __builtin_amdgcn_s_setprio(1);
        #pragma unroll
        for (int nt = 0; nt < 16; nt++) {
            int row = nt * 16 + col;
            #pragma unroll
            for (int ks = 0; ks < 2; ks++) {
                bf16x8 vb = *(const bf16x8*)((const char*)vtb + row * 128 +
                                             ((((ks << 2) + quad) ^ (col & 7)) << 4));
                of[nt] = __builtin_amdgcn_mfma_f32_16x16x32_bf16(pa[ks], vb, of[nt], 0, 0, 0);
            }
        }
        __builtin_amdgcn_s_setprio(0);
    }
#undef STAGE_LOAD
#undef STAGE_WRITE
    #pragma unroll
    for (int r = 0; r < 4; r++) {
        float inv = 1.0f / l_i[r];
        int row = qb + wv * 16 + quad * 4 + r;
        float* dst = o_lat + ((size_t)row * NH + h) * KVLORA + col;
        #pragma unroll
        for (int nt = 0; nt < 16; nt++) dst[nt * 16] = of[nt][r] * inv;
    }
}

// ------- o_bf = o_lat @ w_vc[h] (tiled: 16 t-rows per block, w_vc[h] read once) -------
__global__ __launch_bounds__(256) void ogemm(const float* __restrict__ o_lat,
                                             const float* __restrict__ w_vc,
                                             ushort* __restrict__ o) {
    int tb = blockIdx.x * 16, h = blockIdx.y, tid = threadIdx.x;
    __shared__ float ol[16][KVLORA];
    for (int i = tid; i < 16 * KVLORA; i += 256) {
        int r = i >> 8, k = i & 255;
        ol[r][k] = o_lat[((size_t)(tb + r) * NH + h) * KVLORA + k];
    }
    __syncthreads();
    int v = tid & 63, r0 = tid >> 6;       // 4 rows/thread: r0, r0+4, r0+8, r0+12
    float acc[4] = {0.f, 0.f, 0.f, 0.f};
    const float* w = w_vc + (size_t)h * KVLORA * VDIM + v;
    for (int k = 0; k < KVLORA; k++) {
        float wval = w[(size_t)k * VDIM];
        #pragma unroll
        for (int j = 0; j < 4; j++) acc[j] += ol[r0 + j * 4][k] * wval;
    }
    #pragma unroll
    for (int j = 0; j < 4; j++)
        o[(size_t)(tb + r0 + j * 4) * HID + h * VDIM + v] = f2bf(acc[j]);
}

extern "C" void kernel_launch(void* const* d_in, const int* in_sizes, int n_in,
                              void* d_out, int out_size, void* d_ws, size_t ws_size,
                              hipStream_t stream) {
    const int*   positions = (const int*)d_in[0];
    const float* hs    = (const float*)d_in[1];
    const float* w_qa  = (const float*)d_in[2];
    const float* g_qa  = (const float*)d_in[3];
    const float* w_qb  = (const float*)d_in[4];
    const float* w_kva = (const float*)d_in[5];
    const float* g_kva = (const float*)d_in[6];
    const float* w_kc  = (const float*)d_in[7];
    const float* w_vc  = (const float*)d_in[8];
    const float* w_o   = (const float*)d_in[9];
    float* out = (float*)d_out;

    float* ws    = (float*)d_ws;
    float* qa    = ws;                               // T*768
    float* q     = qa    + (size_t)TT * QLORA;       // T*3840
    float* kin   = q     + (size_t)TT * NH * QHD;    // T*288
    float* o_lat = kin   + (size_t)TT * DQK;         // T*40*256
    ushort* ub     = (ushort*)(o_lat + (size_t)TT * NH * KVLORA);
    ushort* hs_bf  = ub;                             // T*2560
    ushort* qa_bf  = hs_bf  + (size_t)TT * HID;      // T*768
    ushort* o_bf   = qa_bf  + (size_t)TT * QLORA;    // T*2560
    ushort* kin_bf = o_bf   + (size_t)TT * HID;      // T*288
    ushort* qin_bf = kin_bf + (size_t)TT * DQK;      // T*40*288
    ushort* w_qa_t  = qin_bf + (size_t)TT * NH * DQK;       // 768*2560
    ushort* w_qb_t  = w_qa_t + (size_t)QLORA * HID;         // 3840*768
    ushort* w_kva_t = w_qb_t + (size_t)(NH * QHD) * QLORA;  // 288*2560
    ushort* w_o_t   = w_kva_t + (size_t)DQK * HID;          // 2560*2560
    ushort* vtg     = w_o_t + (size_t)HID * HID;            // 256*2048

    // ---- casts / transposes (independent of each other) ----
    cast_bf16<<<(TT * HID) / 1024, 256, 0, stream>>>(hs, hs_bf, TT * HID);
    transpose_cast<<<dim3(QLORA / 32, HID / 32), 256, 0, stream>>>(w_qa, w_qa_t, HID, QLORA);
    transpose_cast<<<dim3((NH * QHD) / 32, QLORA / 32), 256, 0, stream>>>(w_qb, w_qb_t, QLORA, NH * QHD);
    transpose_cast<<<dim3(DQK / 32, HID / 32), 256, 0, stream>>>(w_kva, w_kva_t, HID, DQK);
    transpose_cast<<<dim3(HID / 32, HID / 32), 256, 0, stream>>>(w_o, w_o_t, HID, HID);

    // 1. qa = hs @ w_qa (MFMA); RMS -> qa_bf
    gemm_bf16<<<dim3(QLORA / 128, TT / 128), 256, 0, stream>>>(hs_bf, w_qa_t, qa, TT, QLORA, HID);
    rms_qa<<<TT, 256, 0, stream>>>(qa, g_qa, qa_bf);
    // 2. q = qa @ w_qb (MFMA)
    gemm_bf16<<<dim3((NH * QHD) / 128, TT / 128), 256, 0, stream>>>(qa_bf, w_qb_t, q, TT, NH * QHD, QLORA);
    // 3. kin = hs @ w_kva (MFMA, N=288 edge); RMS+RoPE -> kin_bf
    gemm_bf16<<<dim3((DQK + 127) / 128, TT / 128), 256, 0, stream>>>(hs_bf, w_kva_t, kin, TT, DQK, HID);
    kin_post<<<TT, 256, 0, stream>>>(kin, g_kva, positions, kin_bf);
    // 3b. vtg = transpose of v_in (coalesced V^T staging source for attention)
    transpose_v<<<dim3(TT / 32, KVLORA / 32), 256, 0, stream>>>(kin_bf, vtg);
    // 4. qin_bf = [q_nope @ w_kc[h] | rope(q_pe)] * scale
    build_qin<<<dim3(TT / QTB, NH), 256, 0, stream>>>(q, w_kc, positions, qin_bf);
    // 5. flash MFMA attention (async reg-staged, double-buffered in registers)
    flash_attn<<<dim3(TT / 64, NH), 256, 0, stream>>>(qin_bf, kin_bf, vtg, o_lat);
    // 6. o_bf = o_lat @ w_vc
    ogemm<<<dim3(TT / 16, NH), 256, 0, stream>>>(o_lat, w_vc, o_bf);
    // 7. out = o_bf @ w_o (MFMA)
    gemm_bf16<<<dim3(HID / 128, TT / 128), 256, 0, stream>>>(o_bf, w_o_t, out, TT, HID, HID);
}

// Round 4
// 880.268 us; speedup vs baseline: 1.8394x; 1.4657x over previous
//
#include <hip/hip_runtime.h>
#include <hip/hip_bf16.h>
#include <math.h>

#define TT 2048
#define HID 2560
#define NH 40
#define NOPE 64
#define ROPE 32
#define VDIM 64
#define QLORA 768
#define KVLORA 256
#define DQK 288            // KVLORA + ROPE
#define QHD 96             // NOPE + ROPE
#define EPS 1e-5f
#define THETA 10000.0f

typedef __attribute__((ext_vector_type(8))) short bf16x8;
typedef __attribute__((ext_vector_type(4))) float f32x4;
typedef __attribute__((address_space(1))) const void* gas_t;
typedef __attribute__((address_space(3))) void* las_t;

static __device__ __forceinline__ ushort f2bf(float x) {
    __hip_bfloat16 b = __float2bfloat16(x);
    return *reinterpret_cast<ushort*>(&b);
}

// ---------------- flat fp32 -> bf16 cast ----------------
__global__ __launch_bounds__(256) void cast_bf16(const float* __restrict__ x,
                                                 ushort* __restrict__ y, int n) {
    int i = (blockIdx.x * 256 + threadIdx.x) * 4;
    if (i + 3 < n) {
        float4 v = *(const float4*)(x + i);
        y[i]     = f2bf(v.x);
        y[i + 1] = f2bf(v.y);
        y[i + 2] = f2bf(v.z);
        y[i + 3] = f2bf(v.w);
    }
}

// ------------- transpose + cast: w (K x N fp32) -> wt (N x K bf16) -------------
__global__ __launch_bounds__(256) void transpose_cast(const float* __restrict__ w,
                                                      ushort* __restrict__ wt,
                                                      int K, int N) {
    __shared__ float tile[32][33];
    int bn = blockIdx.x * 32, bk = blockIdx.y * 32;
    int tx = threadIdx.x % 32, ty = threadIdx.x / 32;   // 32 x 8
    #pragma unroll
    for (int i = 0; i < 32; i += 8) {
        int k = bk + ty + i, n = bn + tx;
        if (k < K && n < N) tile[ty + i][tx] = w[(size_t)k * N + n];
    }
    __syncthreads();
    #pragma unroll
    for (int i = 0; i < 32; i += 8) {
        int n = bn + ty + i, k = bk + tx;
        if (n < N && k < K) wt[(size_t)n * K + k] = f2bf(tile[tx][ty + i]);
    }
}

// ------- bf16 MFMA GEMM (m97 structure): C(MxN,f32) = A(MxK,bf16) @ Bt(NxK,bf16)^T -------
__global__ __launch_bounds__(256, 2) void gemm_bf16(const ushort* __restrict__ A,
                                                    const ushort* __restrict__ Bt,
                                                    float* __restrict__ C,
                                                    int M, int N, int K) {
    __shared__ ushort As[128 * 32];
    __shared__ ushort Bs[128 * 32];
    const int tid  = threadIdx.x;
    const int lane = tid & 63;
    const int wv   = tid >> 6;
    const int col  = lane & 15;
    const int quad = lane >> 4;
    const int m0 = blockIdx.y * 128, n0 = blockIdx.x * 128;
    const int wr = (wv >> 1) * 64, wc = (wv & 1) * 64;

    f32x4 acc[4][4];
    #pragma unroll
    for (int i = 0; i < 4; i++)
        #pragma unroll
        for (int j = 0; j < 4; j++) acc[i][j] = (f32x4){0.f, 0.f, 0.f, 0.f};

    for (int k0 = 0; k0 < K; k0 += 32) {
        #pragma unroll
        for (int j = 0; j < 2; j++) {
            int slot = wv * 128 + j * 64 + lane;     // 0..511
            int row  = slot >> 2;
            int ch   = slot & 3;
            const ushort* ga = A + (size_t)(m0 + row) * K + k0 + ch * 8;
            __builtin_amdgcn_global_load_lds((gas_t)ga, (las_t)(As + slot * 8), 16, 0, 0);
            int brow = n0 + row; if (brow >= N) brow = N - 1;   // clamp (edge tiles)
            const ushort* gb = Bt + (size_t)brow * K + k0 + ch * 8;
            __builtin_amdgcn_global_load_lds((gas_t)gb, (las_t)(Bs + slot * 8), 16, 0, 0);
        }
        __syncthreads();
        bf16x8 af[4], bfr[4];
        #pragma unroll
        for (int i = 0; i < 4; i++)
            af[i] = *(const bf16x8*)(As + (wr + i * 16 + col) * 32 + quad * 8);
        #pragma unroll
        for (int j = 0; j < 4; j++)
            bfr[j] = *(const bf16x8*)(Bs + (wc + j * 16 + col) * 32 + quad * 8);
        #pragma unroll
        for (int i = 0; i < 4; i++)
            #pragma unroll
            for (int j = 0; j < 4; j++)
                acc[i][j] = __builtin_amdgcn_mfma_f32_16x16x32_bf16(af[i], bfr[j], acc[i][j], 0, 0, 0);
        __syncthreads();
    }
    #pragma unroll
    for (int i = 0; i < 4; i++) {
        int gr = m0 + wr + i * 16 + quad * 4;
        #pragma unroll
        for (int j = 0; j < 4; j++) {
            int gc = n0 + wc + j * 16 + col;
            if (gc < N) {
                #pragma unroll
                for (int r = 0; r < 4; r++)
                    C[(size_t)(gr + r) * N + gc] = acc[i][j][r];
            }
        }
    }
}

// ---------------- RMS norm: fp32 in, bf16 out ----------------
__global__ __launch_bounds__(256) void rms_qa(const float* __restrict__ x,
                                              const float* __restrict__ g,
                                              ushort* __restrict__ y) {
    int t = blockIdx.x, tid = threadIdx.x;
    __shared__ float red[256];
    __shared__ float s_inv;
    const float* row = x + (size_t)t * QLORA;
    float ss = 0.f;
    for (int i = tid; i < QLORA; i += 256) { float v = row[i]; ss += v * v; }
    red[tid] = ss; __syncthreads();
    for (int s = 128; s > 0; s >>= 1) { if (tid < s) red[tid] += red[tid + s]; __syncthreads(); }
    if (tid == 0) s_inv = rsqrtf(red[0] / (float)QLORA + EPS);
    __syncthreads();
    float si = s_inv;
    ushort* orow = y + (size_t)t * QLORA;
    for (int i = tid; i < QLORA; i += 256) orow[i] = f2bf(row[i] * si * g[i]);
}

// ------- latent post: RMS first 256, RoPE last 32 -> bf16 kin_bf (T x 288) -------
__global__ __launch_bounds__(256) void kin_post(const float* __restrict__ kin,
                                                const float* __restrict__ g,
                                                const int* __restrict__ positions,
                                                ushort* __restrict__ kin_bf) {
    int t = blockIdx.x, tid = threadIdx.x;
    __shared__ float red[256];
    __shared__ float s_inv;
    const float* row = kin + (size_t)t * DQK;
    float v = row[tid];
    red[tid] = v * v; __syncthreads();
    for (int s = 128; s > 0; s >>= 1) { if (tid < s) red[tid] += red[tid + s]; __syncthreads(); }
    if (tid == 0) s_inv = rsqrtf(red[0] / (float)KVLORA + EPS);
    __syncthreads();
    ushort* orow = kin_bf + (size_t)t * DQK;
    orow[tid] = f2bf(v * s_inv * g[tid]);
    if (tid < 16) {
        float pos = (float)positions[t];
        float freq = powf(THETA, -(float)tid / 16.0f);
        float f = pos * freq;
        float c = cosf(f), s = sinf(f);
        float x1 = row[KVLORA + tid], x2 = row[KVLORA + 16 + tid];
        orow[KVLORA + tid]      = f2bf(x1 * c - x2 * s);
        orow[KVLORA + 16 + tid] = f2bf(x2 * c + x1 * s);
    }
}

// --- q_in build (tiled: 16 t-rows per block, w_kc[h] read once per block) ---
#define QTB 16
__global__ __launch_bounds__(256) void build_qin(const float* __restrict__ q,
                                                 const float* __restrict__ w_kc,
                                                 const int* __restrict__ positions,
                                                 ushort* __restrict__ qin) {
    int tb = blockIdx.x * QTB, h = blockIdx.y, tid = threadIdx.x;
    const float scale = 0.10206207261596577f;   // 1/sqrt(96), folded into Q
    __shared__ float qn[QTB][NOPE];
    __shared__ float qp[QTB][ROPE];
    // load 16 q rows (96 floats each)
    for (int i = tid; i < QTB * QHD; i += 256) {
        int r = i / QHD, cidx = i % QHD;
        float v = q[(size_t)(tb + r) * (NH * QHD) + h * QHD + cidx];
        if (cidx < NOPE) qn[r][cidx] = v;
        else             qp[r][cidx - NOPE] = v;
    }
    __syncthreads();
    // each thread owns one latent dim k for all 16 rows
    int k = tid;
    float acc[QTB];
    #pragma unroll
    for (int r = 0; r < QTB; r++) acc[r] = 0.f;
    const float* w = w_kc + (size_t)h * NOPE * KVLORA + k;
    for (int n = 0; n < NOPE; n++) {
        float wval = w[(size_t)n * KVLORA];
        #pragma unroll
        for (int r = 0; r < QTB; r++) acc[r] += qn[r][n] * wval;
    }
    #pragma unroll
    for (int r = 0; r < QTB; r++)
        qin[((size_t)(tb + r) * NH + h) * DQK + k] = f2bf(acc[r] * scale);
    // rope: 16 rows x 16 freqs = 256 threads
    int r = tid >> 4, fi = tid & 15;
    float pos = (float)positions[tb + r];
    float freq = powf(THETA, -(float)fi / 16.0f);
    float f = pos * freq;
    float c = cosf(f), s = sinf(f);
    float x1 = qp[r][fi], x2 = qp[r][16 + fi];
    ushort* orow = qin + ((size_t)(tb + r) * NH + h) * DQK;
    orow[KVLORA + fi]      = f2bf((x1 * c - x2 * s) * scale);
    orow[KVLORA + 16 + fi] = f2bf((x2 * c + x1 * s) * scale);
}

// ---------------- flash MFMA attention (r0 structure, KVBLK=32, 3 blocks/CU) ----------------
// LDS: K tile 32 x KSTR (rope cols inside), V^T tile 256 x VSTR (built from the same
// loads, r0-proven scatter), P buffer dedicated per-wave rows (barrier-free P).
// Total 43.5 KB -> 3 independent blocks/CU: staging drain of one block overlaps
// compute of the other two (latency-bound fix per rocprof: all pipes low + low occ).
#define KVB 32
#define KSTR 296
#define VSTR 40
#define PSTR 40

__global__ __launch_bounds__(256, 3) void flash_attn(const ushort* __restrict__ qin,
                                                     const ushort* __restrict__ kin,
                                                     float* __restrict__ o_lat) {
    __shared__ __align__(16) ushort lds[KVB * KSTR + 256 * VSTR + 64 * PSTR];
    ushort* krow = lds;                       // 32 x 296 (18944 B)
    ushort* vt   = lds + KVB * KSTR;          // 256 x 40 (20480 B)
    ushort* pbuf = vt + 256 * VSTR;           // 64 x 40  (5120 B)

    const int tid  = threadIdx.x;
    const int lane = tid & 63;
    const int wv   = tid >> 6;
    const int col  = lane & 15;
    const int quad = lane >> 4;
    const int h    = blockIdx.y;
    const int qb   = ((int)gridDim.x - 1 - (int)blockIdx.x) * 64;

    // staging geometry: 32 rows x 8 chunk-groups
    const int srow = tid & 31;
    const int sgrp = tid >> 5;                // 0..7

    bf16x8 qf[9];
    {
        const ushort* base = qin + ((size_t)(qb + wv * 16 + col) * NH + h) * DQK + quad * 8;
        #pragma unroll
        for (int k = 0; k < 9; k++) qf[k] = *(const bf16x8*)(base + k * 32);
    }

    f32x4 of[16];
    #pragma unroll
    for (int i = 0; i < 16; i++) of[i] = (f32x4){0.f, 0.f, 0.f, 0.f};
    float m_i[4] = {-1e30f, -1e30f, -1e30f, -1e30f};
    float l_i[4] = {0.f, 0.f, 0.f, 0.f};

    const int rowg = qb + wv * 16 + quad * 4;   // this thread's first q-row

    for (int s0 = 0; s0 <= qb + 32; s0 += KVB) {
        __syncthreads();
        {
            const ushort* src = kin + (size_t)(s0 + srow) * DQK;
            #pragma unroll
            for (int ci = 0; ci < 4; ci++) {         // c = 0..31: K chunk + V scatter
                int c = ci * 8 + sgrp;
                uint4 u = *(const uint4*)(src + c * 8);
                *(uint4*)(krow + srow * KSTR + c * 8) = u;
                const ushort* up = (const ushort*)&u;
                #pragma unroll
                for (int j = 0; j < 8; j++)
                    vt[(c * 8 + j) * VSTR + srow] = up[j];
            }
            if (sgrp < 4) {                          // c = 32..35: rope cols, K only
                int c = 32 + sgrp;
                uint4 u = *(const uint4*)(src + c * 8);
                *(uint4*)(krow + srow * KSTR + c * 8) = u;
            }
        }
        __syncthreads();

        // ---- QK^T ----
        f32x4 sf[2];
        sf[0] = (f32x4){0.f, 0.f, 0.f, 0.f};
        sf[1] = (f32x4){0.f, 0.f, 0.f, 0.f};
        __builtin_amdgcn_s_setprio(1);
        #pragma unroll
        for (int k = 0; k < 9; k++) {
            #pragma unroll
            for (int tc = 0; tc < 2; tc++) {
                bf16x8 bf = *(const bf16x8*)(krow + (tc * 16 + col) * KSTR + k * 32 + quad * 8);
                sf[tc] = __builtin_amdgcn_mfma_f32_16x16x32_bf16(qf[k], bf, sf[tc], 0, 0, 0);
            }
        }
        __builtin_amdgcn_s_setprio(0);

        // causal mask (always on: diagonal spans the last two 32-tiles)
        #pragma unroll
        for (int tc = 0; tc < 2; tc++)
            #pragma unroll
            for (int r = 0; r < 4; r++)
                if (s0 + tc * 16 + col > rowg + r) sf[tc][r] = -1e30f;

        float mnew[4], alpha[4];
        #pragma unroll
        for (int r = 0; r < 4; r++) {
            float mx = fmaxf(sf[0][r], sf[1][r]);
            mx = fmaxf(mx, __shfl_xor(mx, 1));
            mx = fmaxf(mx, __shfl_xor(mx, 2));
            mx = fmaxf(mx, __shfl_xor(mx, 4));
            mx = fmaxf(mx, __shfl_xor(mx, 8));
            mnew[r] = fmaxf(m_i[r], mx);
            alpha[r] = __expf(m_i[r] - mnew[r]);
            m_i[r] = mnew[r];
        }
        float rsum[4];
        #pragma unroll
        for (int r = 0; r < 4; r++) {
            float s = 0.f;
            #pragma unroll
            for (int tc = 0; tc < 2; tc++) {
                float p = __expf(sf[tc][r] - mnew[r]);
                sf[tc][r] = p;
                s += p;
            }
            s += __shfl_xor(s, 1);
            s += __shfl_xor(s, 2);
            s += __shfl_xor(s, 4);
            s += __shfl_xor(s, 8);
            rsum[r] = s;
        }
        #pragma unroll
        for (int r = 0; r < 4; r++) l_i[r] = l_i[r] * alpha[r] + rsum[r];
        #pragma unroll
        for (int i = 0; i < 16; i++)
            #pragma unroll
            for (int r = 0; r < 4; r++) of[i][r] *= alpha[r];

        // ---- P -> pbuf (per-wave private rows: no barrier needed) ----
        #pragma unroll
        for (int tc = 0; tc < 2; tc++)
            #pragma unroll
            for (int r = 0; r < 4; r++)
                pbuf[(wv * 16 + quad * 4 + r) * PSTR + tc * 16 + col] = f2bf(sf[tc][r]);
        bf16x8 pa = *(const bf16x8*)(pbuf + (wv * 16 + col) * PSTR + quad * 8);

        // ---- PV ----
        __builtin_amdgcn_s_setprio(1);
        #pragma unroll
        for (int nt = 0; nt < 16; nt++) {
            bf16x8 vb = *(const bf16x8*)(vt + (nt * 16 + col) * VSTR + quad * 8);
            of[nt] = __builtin_amdgcn_mfma_f32_16x16x32_bf16(pa, vb, of[nt], 0, 0, 0);
        }
        __builtin_amdgcn_s_setprio(0);
    }
    #pragma unroll
    for (int r = 0; r < 4; r++) {
        float inv = 1.0f / l_i[r];
        int row = qb + wv * 16 + quad * 4 + r;
        float* dst = o_lat + ((size_t)row * NH + h) * KVLORA + col;
        #pragma unroll
        for (int nt = 0; nt < 16; nt++) dst[nt * 16] = of[nt][r] * inv;
    }
}

// ------- o_bf = o_lat @ w_vc[h] (tiled: 16 t-rows per block, w_vc[h] read once) -------
__global__ __launch_bounds__(256) void ogemm(const float* __restrict__ o_lat,
                                             const float* __restrict__ w_vc,
                                             ushort* __restrict__ o) {
    int tb = blockIdx.x * 16, h = blockIdx.y, tid = threadIdx.x;
    __shared__ float ol[16][KVLORA];
    for (int i = tid; i < 16 * KVLORA; i += 256) {
        int r = i >> 8, k = i & 255;
        ol[r][k] = o_lat[((size_t)(tb + r) * NH + h) * KVLORA + k];
    }
    __syncthreads();
    int v = tid & 63, r0 = tid >> 6;       // 4 rows/thread: r0, r0+4, r0+8, r0+12
    float acc[4] = {0.f, 0.f, 0.f, 0.f};
    const float* w = w_vc + (size_t)h * KVLORA * VDIM + v;
    for (int k = 0; k < KVLORA; k++) {
        float wval = w[(size_t)k * VDIM];
        #pragma unroll
        for (int j = 0; j < 4; j++) acc[j] += ol[r0 + j * 4][k] * wval;
    }
    #pragma unroll
    for (int j = 0; j < 4; j++)
        o[(size_t)(tb + r0 + j * 4) * HID + h * VDIM + v] = f2bf(acc[j]);
}

extern "C" void kernel_launch(void* const* d_in, const int* in_sizes, int n_in,
                              void* d_out, int out_size, void* d_ws, size_t ws_size,
                              hipStream_t stream) {
    const int*   positions = (const int*)d_in[0];
    const float* hs    = (const float*)d_in[1];
    const float* w_qa  = (const float*)d_in[2];
    const float* g_qa  = (const float*)d_in[3];
    const float* w_qb  = (const float*)d_in[4];
    const float* w_kva = (const float*)d_in[5];
    const float* g_kva = (const float*)d_in[6];
    const float* w_kc  = (const float*)d_in[7];
    const float* w_vc  = (const float*)d_in[8];
    const float* w_o   = (const float*)d_in[9];
    float* out = (float*)d_out;

    float* ws    = (float*)d_ws;
    float* qa    = ws;                               // T*768
    float* q     = qa    + (size_t)TT * QLORA;       // T*3840
    float* kin   = q     + (size_t)TT * NH * QHD;    // T*288
    float* o_lat = kin   + (size_t)TT * DQK;         // T*40*256
    ushort* ub     = (ushort*)(o_lat + (size_t)TT * NH * KVLORA);
    ushort* hs_bf  = ub;                             // T*2560
    ushort* qa_bf  = hs_bf  + (size_t)TT * HID;      // T*768
    ushort* o_bf   = qa_bf  + (size_t)TT * QLORA;    // T*2560
    ushort* kin_bf = o_bf   + (size_t)TT * HID;      // T*288
    ushort* qin_bf = kin_bf + (size_t)TT * DQK;      // T*40*288
    ushort* w_qa_t  = qin_bf + (size_t)TT * NH * DQK;       // 768*2560
    ushort* w_qb_t  = w_qa_t + (size_t)QLORA * HID;         // 3840*768
    ushort* w_kva_t = w_qb_t + (size_t)(NH * QHD) * QLORA;  // 288*2560
    ushort* w_o_t   = w_kva_t + (size_t)DQK * HID;          // 2560*2560

    // ---- casts / transposes (independent of each other) ----
    cast_bf16<<<(TT * HID) / 1024, 256, 0, stream>>>(hs, hs_bf, TT * HID);
    transpose_cast<<<dim3(QLORA / 32, HID / 32), 256, 0, stream>>>(w_qa, w_qa_t, HID, QLORA);
    transpose_cast<<<dim3((NH * QHD) / 32, QLORA / 32), 256, 0, stream>>>(w_qb, w_qb_t, QLORA, NH * QHD);
    transpose_cast<<<dim3(DQK / 32, HID / 32), 256, 0, stream>>>(w_kva, w_kva_t, HID, DQK);
    transpose_cast<<<dim3(HID / 32, HID / 32), 256, 0, stream>>>(w_o, w_o_t, HID, HID);

    // 1. qa = hs @ w_qa (MFMA); RMS -> qa_bf
    gemm_bf16<<<dim3(QLORA / 128, TT / 128), 256, 0, stream>>>(hs_bf, w_qa_t, qa, TT, QLORA, HID);
    rms_qa<<<TT, 256, 0, stream>>>(qa, g_qa, qa_bf);
    // 2. q = qa @ w_qb (MFMA)
    gemm_bf16<<<dim3((NH * QHD) / 128, TT / 128), 256, 0, stream>>>(qa_bf, w_qb_t, q, TT, NH * QHD, QLORA);
    // 3. kin = hs @ w_kva (MFMA, N=288 edge); RMS+RoPE -> kin_bf
    gemm_bf16<<<dim3((DQK + 127) / 128, TT / 128), 256, 0, stream>>>(hs_bf, w_kva_t, kin, TT, DQK, HID);
    kin_post<<<TT, 256, 0, stream>>>(kin, g_kva, positions, kin_bf);
    // 4. qin_bf = [q_nope @ w_kc[h] | rope(q_pe)] * scale
    build_qin<<<dim3(TT / QTB, NH), 256, 0, stream>>>(q, w_kc, positions, qin_bf);
    // 5. flash MFMA attention (KVBLK=32, 3 blocks/CU)
    flash_attn<<<dim3(TT / 64, NH), 256, 0, stream>>>(qin_bf, kin_bf, o_lat);
    // 6. o_bf = o_lat @ w_vc
    ogemm<<<dim3(TT / 16, NH), 256, 0, stream>>>(o_lat, w_vc, o_bf);
    // 7. out = o_bf @ w_o (MFMA)
    gemm_bf16<<<dim3(HID / 128, TT / 128), 256, 0, stream>>>(o_bf, w_o_t, out, TT, HID, HID);
}